// Round 6
// baseline (178.277 us; speedup 1.0000x reference)
//
#include <hip/hip_runtime.h>
#include <hip/hip_bf16.h>
#include <hip/hip_fp16.h>

#define BB 4
#define HH 160
#define WW 160
#define HWD (HH * WW)                   // 25600
#define OUT_ELEMS (BB * 64 * HWD)       // 6,553,600
#define EPSBN 1e-5f
#define CHSTRIDE (8 * HWD)              // 8-channel chunk stride
#define NSLOT 256                       // BN partial slots per channel-stat

typedef _Float16 f16x8 __attribute__((ext_vector_type(8)));
typedef __attribute__((ext_vector_type(4))) float f32x4;

__device__ inline unsigned short f16bits(float a) {
  _Float16 h = (_Float16)a;
  unsigned short u;
  __builtin_memcpy(&u, &h, 2);
  return u;
}
__device__ inline unsigned packh2(float a, float b) {
  return (unsigned)f16bits(a) | ((unsigned)f16bits(b) << 16);
}

// XCD-slab tile mapping: blk%8 = XCD; each XCD owns 200 contiguous tiles
// (an 80-row band) so halo re-reads stay inside one 4MB L2.
__device__ inline void tile_map(int blk, int& b, int& ty0, int& tx0) {
  int t = (blk & 7) * 200 + (blk >> 3);
  b = t / 400;
  int r = t % 400;
  ty0 = (r / 10) * 4;
  tx0 = (r % 10) * 16;
}

// ---------------------------------------------------------------------------
// prep: f16 prepacked MFMA B-fragments (K permuted: kappa = tap*8 + ch within
// each 8-ch chunk, 96-padded; taps 9..11 zero rows) + zero BN partial slots.
// Bp[nt][ki=chunk*3+kk][lane][j]: B[kappa=kk*32+(l>>4)*8+j][n=nt*16+(l&15)]
// ---------------------------------------------------------------------------
__global__ void prep_kernel(const float* __restrict__ cw,
                            const float* __restrict__ ow,
                            unsigned short* __restrict__ Bp,
                            unsigned short* __restrict__ B2p,
                            float* __restrict__ part) {
  int i = blockIdx.x * 256 + threadIdx.x;
  if (i < 32768) part[i] = 0.f;
  if (i < 49152) {                      // dconv weights conv_w[n][c][t], nt 0..3
    int j = i & 7, l = (i >> 3) & 63, rest = i >> 9;
    int ki = rest % 24, nt = rest / 24;
    int kp = ki * 32 + ((l >> 4) << 3) + j;
    int chunk = kp / 96, kq = kp % 96;
    int t = kq >> 3, c = kq & 7;
    int n = nt * 16 + (l & 15);
    float v = (t < 9) ? cw[n * 576 + (chunk * 8 + c) * 9 + t] : 0.f;
    Bp[i] = f16bits(v);
  }
  if (i < 24576) {                      // offconv weights, nt 0..1, n<18
    int j = i & 7, l = (i >> 3) & 63, rest = i >> 9;
    int ki = rest % 24, nt = rest / 24;
    int kp = ki * 32 + ((l >> 4) << 3) + j;
    int chunk = kp / 96, kq = kp % 96;
    int t = kq >> 3, c = kq & 7;
    int n = nt * 16 + (l & 15);
    float v = (t < 9 && n < 18) ? ow[n * 576 + (chunk * 8 + c) * 9 + t] : 0.f;
    B2p[i] = f16bits(v);
  }
}

// ---------------------------------------------------------------------------
// Fused offconv + dconv. One block = 16x4 pixel tile, grid 1600 (XCD-slab).
// Phase A (offconv GEMM M=64,N=32,K=576pad768): d staged as packed-f16 pairs
// (pixel-major, 16B/pixel); A-operands read DIRECTLY from patch (tap octet =
// one b128) -> MFMA f16; clamped offsets -> LDS offbuf + global (output #2).
// Phase B (dconv GEMM M=64,N=64): x staged same way; bilinear interp in
// packed __half2 (one b128 per corner), result = A-fragment -> Af -> MFMA.
// BN partial sums fused into epilogue.
// ---------------------------------------------------------------------------
__global__ __launch_bounds__(256) void fused_kernel(
    const float* __restrict__ x, const float* __restrict__ d,
    const f16x8* __restrict__ Bp, const f16x8* __restrict__ B2p,
    float* __restrict__ out, float* __restrict__ off_out,
    float* __restrict__ part) {
  int b, ty0, tx0;
  tile_map(blockIdx.x, b, ty0, tx0);
  const int tid = threadIdx.x;
  const int wv = tid >> 6, lane = tid & 63;
  const int lo = lane >> 4, li = lane & 15;

  __shared__ __align__(16) unsigned patch2[756];  // 189px x 8ch f16 (B) / 108px (A)
  __shared__ f16x8 Af[768];                       // [mf*3+kk][lane]
  __shared__ float offbuf[64 * 19];               // [pixel m][n], stride 19

  // ---- phase A staging descriptors: d, 6x18 area, 432 u32 slots
  int gdo[2], gdl[2];
  bool gdk[2];
#pragma unroll
  for (int i = 0; i < 2; ++i) {
    int l = tid + i * 256;
    int p = l % 108, c2 = l / 108;
    int r = p / 18, col = p % 18;
    int gy = ty0 - 1 + r, gx = tx0 - 1 + col;
    gdk[i] = (l < 432) && gy >= 0 && gy < HH && gx >= 0 && gx < WW;
    gdo[i] = ((b * 64 + 2 * c2) * HH + gy) * WW + gx;
    gdl[i] = p * 4 + c2;
  }
  unsigned gd[2];
#pragma unroll
  for (int i = 0; i < 2; ++i)
    gd[i] = gdk[i] ? packh2(d[gdo[i]], d[gdo[i] + HWD]) : 0u;

  // ---- phase B staging descriptors: x, 9x21 area, 756 u32 slots
  int gxo[3], gxl[3];
  bool gxk[3];
#pragma unroll
  for (int i = 0; i < 3; ++i) {
    int l = tid + i * 256;
    int p = l % 189, c2 = l / 189;
    int r = p / 21, col = p % 21;
    int gy = ty0 - 2 + r, gx2 = tx0 - 2 + col;
    gxk[i] = (l < 756) && gy >= 0 && gy < HH && gx2 >= 0 && gx2 < WW;
    gxo[i] = ((b * 64 + 2 * c2) * HH + gy) * WW + gx2;
    gxl[i] = p * 4 + c2;
  }
  unsigned gx[3];

  // ================= phase A: offset conv =================
  f32x4 acc0{0.f, 0.f, 0.f, 0.f}, acc1{0.f, 0.f, 0.f, 0.f};
  const int nt = wv >> 1, mh = wv & 1;
  int poffA[3];                         // direct A-read pixel offset (u32)
#pragma unroll
  for (int kk = 0; kk < 3; ++kk) {
    int t = kk * 4 + lo;
    if (t > 8) t = 8;                   // taps 9..11: B rows are zero
    poffA[kk] = ((t / 3) * 18 + t % 3 + li) * 4;
  }

  for (int chunk = 0; chunk < 8; ++chunk) {
    f16x8 bw0 = B2p[((nt * 24 + chunk * 3 + 0) << 6) + lane];
    f16x8 bw1 = B2p[((nt * 24 + chunk * 3 + 1) << 6) + lane];
    f16x8 bw2 = B2p[((nt * 24 + chunk * 3 + 2) << 6) + lane];
#pragma unroll
    for (int i = 0; i < 2; ++i)
      if (tid + i * 256 < 432) patch2[gdl[i]] = gd[i];
    __syncthreads();
    if (chunk < 7) {
      int nco = (chunk + 1) * CHSTRIDE;
#pragma unroll
      for (int i = 0; i < 2; ++i)
        gd[i] = gdk[i] ? packh2(d[gdo[i] + nco], d[gdo[i] + nco + HWD]) : 0u;
    } else {                            // prefetch x chunk 0 for phase B
#pragma unroll
      for (int i = 0; i < 3; ++i)
        gx[i] = gxk[i] ? packh2(x[gxo[i]], x[gxo[i] + HWD]) : 0u;
    }
#pragma unroll
    for (int kk = 0; kk < 3; ++kk) {
      f16x8 bw = (kk == 0) ? bw0 : (kk == 1) ? bw1 : bw2;
      const f16x8* a0 = (const f16x8*)(patch2 + poffA[kk] + (mh * 2) * 72);
      const f16x8* a1 = (const f16x8*)(patch2 + poffA[kk] + (mh * 2 + 1) * 72);
      acc0 = __builtin_amdgcn_mfma_f32_16x16x32_f16(*a0, bw, acc0, 0, 0, 0);
      acc1 = __builtin_amdgcn_mfma_f32_16x16x32_f16(*a1, bw, acc1, 0, 0, 0);
    }
    __syncthreads();
  }

  // phase A epilogue: clamp; write offbuf (LDS) + off_out (global, output #2)
  const int nA = nt * 16 + li;
  if (nA < 18) {
#pragma unroll
    for (int f = 0; f < 2; ++f) {
      int mf = mh * 2 + f;
      f32x4 a = f ? acc1 : acc0;
      float4 v;
      v.x = fminf(1.f, fmaxf(-1.f, a[0]));
      v.y = fminf(1.f, fmaxf(-1.f, a[1]));
      v.z = fminf(1.f, fmaxf(-1.f, a[2]));
      v.w = fminf(1.f, fmaxf(-1.f, a[3]));
      offbuf[(mf * 16 + lo * 4 + 0) * 19 + nA] = v.x;
      offbuf[(mf * 16 + lo * 4 + 1) * 19 + nA] = v.y;
      offbuf[(mf * 16 + lo * 4 + 2) * 19 + nA] = v.z;
      offbuf[(mf * 16 + lo * 4 + 3) * 19 + nA] = v.w;
      *(float4*)(off_out + ((b * 18 + nA) * HH + ty0 + mf) * WW + tx0 +
                 lo * 4) = v;
    }
  }
  __syncthreads();                      // offbuf ready

  // ================= phase B: deformable conv =================
  const int h = ty0 + wv, w = tx0 + li;
  const int m_pix = wv * 16 + li;
  int bs[3];
  bool tre[3];
  __half2 w00h[3], w01h[3], w10h[3], w11h[3];
#pragma unroll
  for (int kk = 0; kk < 3; ++kk) {
    int t = kk * 4 + lo;
    tre[kk] = (t < 9);
    if (tre[kk]) {
      float dy = offbuf[m_pix * 19 + 2 * t];
      float dx = offbuf[m_pix * 19 + 2 * t + 1];
      float pyf = (float)(h - 1 + t / 3) + dy;
      float pxf = (float)(w - 1 + t % 3) + dx;
      float y0 = floorf(pyf), x0 = floorf(pxf);
      float wy = pyf - y0, wx = pxf - x0;
      bs[kk] = (((int)y0 - (ty0 - 2)) * 21 + ((int)x0 - (tx0 - 2))) * 4;
      w00h[kk] = __float2half2_rn((1.f - wy) * (1.f - wx));
      w01h[kk] = __float2half2_rn((1.f - wy) * wx);
      w10h[kk] = __float2half2_rn(wy * (1.f - wx));
      w11h[kk] = __float2half2_rn(wy * wx);
    } else {
      bs[kk] = 0;
      w00h[kk] = w01h[kk] = w10h[kk] = w11h[kk] = __float2half2_rn(0.f);
    }
  }

  f32x4 acc[4];
#pragma unroll
  for (int i = 0; i < 4; ++i) acc[i] = f32x4{0.f, 0.f, 0.f, 0.f};

  union u4h { uint4 q; __half2 hh[4]; unsigned u[4]; f16x8 v; };

  for (int chunk = 0; chunk < 8; ++chunk) {
    f16x8 bw0 = Bp[((wv * 24 + chunk * 3 + 0) << 6) + lane];
    f16x8 bw1 = Bp[((wv * 24 + chunk * 3 + 1) << 6) + lane];
    f16x8 bw2 = Bp[((wv * 24 + chunk * 3 + 2) << 6) + lane];
#pragma unroll
    for (int i = 0; i < 3; ++i)
      if (tid + i * 256 < 756) patch2[gxl[i]] = gx[i];
    __syncthreads();
    if (chunk < 7) {
      int nco = (chunk + 1) * CHSTRIDE;
#pragma unroll
      for (int i = 0; i < 3; ++i)
        gx[i] = gxk[i] ? packh2(x[gxo[i] + nco], x[gxo[i] + nco + HWD]) : 0u;
    }
#pragma unroll
    for (int kk = 0; kk < 3; ++kk) {
      u4h a;
      if (tre[kk]) {
        u4h q00, q01, q10, q11;
        q00.q = *(const uint4*)(patch2 + bs[kk]);        // corner (0,0) ch0-7
        q01.q = *(const uint4*)(patch2 + bs[kk] + 4);    // (0,1)
        q10.q = *(const uint4*)(patch2 + bs[kk] + 84);   // (1,0): +21px
        q11.q = *(const uint4*)(patch2 + bs[kk] + 88);   // (1,1)
#pragma unroll
        for (int j = 0; j < 4; ++j) {
          __half2 v = __hmul2(w00h[kk], q00.hh[j]);
          v = __hfma2(w01h[kk], q01.hh[j], v);
          v = __hfma2(w10h[kk], q10.hh[j], v);
          v = __hfma2(w11h[kk], q11.hh[j], v);
          a.hh[j] = v;
        }
      } else {
        a.u[0] = a.u[1] = a.u[2] = a.u[3] = 0u;
      }
      Af[((wv * 3 + kk) << 6) + lane] = a.v;
    }
    __syncthreads();
#pragma unroll
    for (int kk = 0; kk < 3; ++kk) {
      f16x8 bw = (kk == 0) ? bw0 : (kk == 1) ? bw1 : bw2;
#pragma unroll
      for (int mf = 0; mf < 4; ++mf)
        acc[mf] = __builtin_amdgcn_mfma_f32_16x16x32_f16(
            Af[((mf * 3 + kk) << 6) + lane], bw, acc[mf], 0, 0, 0);
    }
  }

  // epilogue: aligned float4 stores + fused BN partial sums
  const int n = wv * 16 + li;
  float s = 0.f, s2 = 0.f;
#pragma unroll
  for (int mf = 0; mf < 4; ++mf) {
    float* po = out + ((b * 64 + n) * HH + ty0 + mf) * WW + tx0 + lo * 4;
    *(float4*)po = make_float4(acc[mf][0], acc[mf][1], acc[mf][2], acc[mf][3]);
#pragma unroll
    for (int r = 0; r < 4; ++r) {
      float v = acc[mf][r];
      s += v;
      s2 = fmaf(v, v, s2);
    }
  }
  s += __shfl_xor(s, 16);
  s += __shfl_xor(s, 32);
  s2 += __shfl_xor(s2, 16);
  s2 += __shfl_xor(s2, 32);
  if (lo == 0) {
    int slot = blockIdx.x & (NSLOT - 1);
    atomicAdd(&part[n * NSLOT + slot], s);
    atomicAdd(&part[(64 + n) * NSLOT + slot], s2);
  }
}

// ---------------------------------------------------------------------------
// reduce BN partials: block j sums part[j][0..255] (f64) -> sums[j]
// ---------------------------------------------------------------------------
__global__ __launch_bounds__(256) void reduce_kernel(
    const float* __restrict__ part, double* __restrict__ sums) {
  const int j = blockIdx.x;
  __shared__ double sh[256];
  sh[threadIdx.x] = (double)part[j * NSLOT + threadIdx.x];
  __syncthreads();
  for (int t = 128; t > 0; t >>= 1) {
    if (threadIdx.x < t) sh[threadIdx.x] += sh[threadIdx.x + t];
    __syncthreads();
  }
  if (threadIdx.x == 0) sums[j] = sh[0];
}

// ---------------------------------------------------------------------------
// BN apply + ReLU, in place on d_out's conv region (float4 vectorized).
// ---------------------------------------------------------------------------
__global__ __launch_bounds__(256) void bnapply_kernel(
    float* __restrict__ out, const double* __restrict__ sums,
    const float* __restrict__ gamma, const float* __restrict__ beta) {
  const int i = blockIdx.x * 256 + threadIdx.x;
  if (i >= OUT_ELEMS / 4) return;
  const int o = (i / (HWD / 4)) & 63;
  const float n_inv = 1.0f / (float)(BB * HWD);
  float mean = (float)sums[o] * n_inv;
  float var = (float)sums[64 + o] * n_inv - mean * mean;
  float inv = gamma[o] * rsqrtf(var + EPSBN);
  float bt = beta[o];
  float4 v = ((float4*)out)[i];
  v.x = fmaxf(0.f, (v.x - mean) * inv + bt);
  v.y = fmaxf(0.f, (v.y - mean) * inv + bt);
  v.z = fmaxf(0.f, (v.z - mean) * inv + bt);
  v.w = fmaxf(0.f, (v.w - mean) * inv + bt);
  ((float4*)out)[i] = v;
}

extern "C" void kernel_launch(void* const* d_in, const int* in_sizes, int n_in,
                              void* d_out, int out_size, void* d_ws, size_t ws_size,
                              hipStream_t stream) {
  const float* x = (const float*)d_in[0];
  const float* d = (const float*)d_in[1];
  const float* ow = (const float*)d_in[2];
  const float* cw = (const float*)d_in[3];
  const float* gamma = (const float*)d_in[4];
  const float* beta = (const float*)d_in[5];

  float* out = (float*)d_out;
  float* off_out = out + OUT_ELEMS;

  // ws: sums double[128] | Bp ush[49152] | B2p ush[24576] | part f32[32768]
  double* sums = (double*)d_ws;
  unsigned short* Bp = (unsigned short*)((char*)d_ws + 1024);
  unsigned short* B2p = Bp + 49152;
  float* part = (float*)(B2p + 24576);

  prep_kernel<<<192, 256, 0, stream>>>(cw, ow, Bp, B2p, part);

  fused_kernel<<<1600, 256, 0, stream>>>(
      x, d, (const f16x8*)Bp, (const f16x8*)B2p, out, off_out, part);

  reduce_kernel<<<128, 256, 0, stream>>>(part, sums);
  bnapply_kernel<<<(OUT_ELEMS / 4 + 255) / 256, 256, 0, stream>>>(
      out, sums, gamma, beta);
}

// Round 8
// 173.941 us; speedup vs baseline: 1.0249x; 1.0249x over previous
//
#include <hip/hip_runtime.h>
#include <hip/hip_fp16.h>

#define BB 4
#define HH 160
#define WW 160
#define HWD (HH * WW)                   // 25600
#define OUT_ELEMS (BB * 64 * HWD)       // 6,553,600
#define EPSBN 1e-5f
#define CHSTRIDE (8 * HWD)              // 8-channel chunk stride
#define NSLOT 256                       // BN partial slots per channel-stat

typedef _Float16 f16x8 __attribute__((ext_vector_type(8)));
typedef __attribute__((ext_vector_type(4))) float f32x4;

__device__ inline unsigned short f16bits(float a) {
  _Float16 h = (_Float16)a;
  unsigned short u;
  __builtin_memcpy(&u, &h, 2);
  return u;
}
__device__ inline unsigned packh2(float a, float b) {
  return (unsigned)f16bits(a) | ((unsigned)f16bits(b) << 16);
}

// XCD-slab tile mapping: blk%8 = XCD; each XCD owns 200 contiguous tiles
// (an 80-row band) so halo re-reads stay inside one 4MB L2.
__device__ inline void tile_map(int blk, int& b, int& ty0, int& tx0) {
  int t = (blk & 7) * 200 + (blk >> 3);
  b = t / 400;
  int r = t % 400;
  ty0 = (r / 10) * 4;
  tx0 = (r % 10) * 16;
}

// ---------------------------------------------------------------------------
// prep: f16 prepacked MFMA B-fragments (K permuted: kappa = tap*8 + ch within
// each 8-ch chunk, 96-padded; taps 9..11 zero rows) + zero BN partial slots.
// ---------------------------------------------------------------------------
__global__ void prep_kernel(const float* __restrict__ cw,
                            const float* __restrict__ ow,
                            unsigned short* __restrict__ Bp,
                            unsigned short* __restrict__ B2p,
                            float* __restrict__ part) {
  int i = blockIdx.x * 256 + threadIdx.x;
  if (i < 32768) part[i] = 0.f;
  if (i < 49152) {                      // dconv weights conv_w[n][c][t]
    int j = i & 7, l = (i >> 3) & 63, rest = i >> 9;
    int ki = rest % 24, nt = rest / 24;
    int kp = ki * 32 + ((l >> 4) << 3) + j;
    int chunk = kp / 96, kq = kp % 96;
    int t = kq >> 3, c = kq & 7;
    int n = nt * 16 + (l & 15);
    float v = (t < 9) ? cw[n * 576 + (chunk * 8 + c) * 9 + t] : 0.f;
    Bp[i] = f16bits(v);
  }
  if (i < 24576) {                      // offconv weights, n<18
    int j = i & 7, l = (i >> 3) & 63, rest = i >> 9;
    int ki = rest % 24, nt = rest / 24;
    int kp = ki * 32 + ((l >> 4) << 3) + j;
    int chunk = kp / 96, kq = kp % 96;
    int t = kq >> 3, c = kq & 7;
    int n = nt * 16 + (l & 15);
    float v = (t < 9 && n < 18) ? ow[n * 576 + (chunk * 8 + c) * 9 + t] : 0.f;
    B2p[i] = f16bits(v);
  }
}

// ---------------------------------------------------------------------------
// Fused offconv + dconv (ordinary launch, grid 1600, XCD-slab).
// Staging slots are c2-FASTEST: slot l -> pixel p=l>>2, chan-pair c2=l&3, so
// the LDS write address IS l (dense, zero bank conflicts). Phase A reads
// A-operands directly from the f16 patch; phase B does packed-half2 bilinear
// interp (one b128 per corner) -> Af -> MFMA. BN partials fused in epilogue.
// ---------------------------------------------------------------------------
__global__ __launch_bounds__(256) void fused_kernel(
    const float* __restrict__ x, const float* __restrict__ d,
    const f16x8* __restrict__ Bp, const f16x8* __restrict__ B2p,
    float* __restrict__ out, float* __restrict__ off_out,
    float* __restrict__ part) {
  int b, ty0, tx0;
  tile_map(blockIdx.x, b, ty0, tx0);
  const int tid = threadIdx.x;
  const int wv = tid >> 6, lane = tid & 63;
  const int lo = lane >> 4, li = lane & 15;

  __shared__ __align__(16) unsigned patch2[756];  // 189px x 8ch f16
  __shared__ f16x8 Af[768];                       // [mf*3+kk][lane]
  __shared__ __align__(16) float offbuf[64 * 19]; // [pixel m][n]

  // ---- phase A staging: d, 6x18 area, 432 u32 slots (c2-fastest)
  int gdo[2];
  bool gdk[2];
#pragma unroll
  for (int i = 0; i < 2; ++i) {
    int l = tid + i * 256;
    int p = l >> 2, c2 = l & 3;
    int r = p / 18, col = p % 18;
    int gy = ty0 - 1 + r, gx = tx0 - 1 + col;
    gdk[i] = (l < 432) && gy >= 0 && gy < HH && gx >= 0 && gx < WW;
    gdo[i] = ((b * 64 + 2 * c2) * HH + gy) * WW + gx;
  }
  unsigned gd[2];
#pragma unroll
  for (int i = 0; i < 2; ++i)
    gd[i] = gdk[i] ? packh2(d[gdo[i]], d[gdo[i] + HWD]) : 0u;

  // ---- phase B staging: x, 9x21 area, 756 u32 slots (c2-fastest)
  int gxo[3];
  bool gxk[3];
#pragma unroll
  for (int i = 0; i < 3; ++i) {
    int l = tid + i * 256;
    int p = l >> 2, c2 = l & 3;
    int r = p / 21, col = p % 21;
    int gy = ty0 - 2 + r, gx2 = tx0 - 2 + col;
    gxk[i] = (l < 756) && gy >= 0 && gy < HH && gx2 >= 0 && gx2 < WW;
    gxo[i] = ((b * 64 + 2 * c2) * HH + gy) * WW + gx2;
  }
  unsigned gx[3];

  // ================= phase A: offset conv =================
  f32x4 acc0{0.f, 0.f, 0.f, 0.f}, acc1{0.f, 0.f, 0.f, 0.f};
  const int nt = wv >> 1, mh = wv & 1;
  int poffA[3];
#pragma unroll
  for (int kk = 0; kk < 3; ++kk) {
    int t = kk * 4 + lo;
    if (t > 8) t = 8;                   // taps 9..11: B rows are zero
    poffA[kk] = ((t / 3) * 18 + t % 3 + li) * 4;
  }

  for (int chunk = 0; chunk < 8; ++chunk) {
    f16x8 bw0 = B2p[((nt * 24 + chunk * 3 + 0) << 6) + lane];
    f16x8 bw1 = B2p[((nt * 24 + chunk * 3 + 1) << 6) + lane];
    f16x8 bw2 = B2p[((nt * 24 + chunk * 3 + 2) << 6) + lane];
#pragma unroll
    for (int i = 0; i < 2; ++i) {
      int l = tid + i * 256;
      if (l < 432) patch2[l] = gd[i];
    }
    __syncthreads();
    if (chunk < 7) {
      int nco = (chunk + 1) * CHSTRIDE;
#pragma unroll
      for (int i = 0; i < 2; ++i)
        gd[i] = gdk[i] ? packh2(d[gdo[i] + nco], d[gdo[i] + nco + HWD]) : 0u;
    } else {                            // prefetch x chunk 0 for phase B
#pragma unroll
      for (int i = 0; i < 3; ++i)
        gx[i] = gxk[i] ? packh2(x[gxo[i]], x[gxo[i] + HWD]) : 0u;
    }
#pragma unroll
    for (int kk = 0; kk < 3; ++kk) {
      f16x8 bw = (kk == 0) ? bw0 : (kk == 1) ? bw1 : bw2;
      const f16x8* a0 = (const f16x8*)(patch2 + poffA[kk] + (mh * 2) * 72);
      const f16x8* a1 = (const f16x8*)(patch2 + poffA[kk] + (mh * 2 + 1) * 72);
      acc0 = __builtin_amdgcn_mfma_f32_16x16x32_f16(*a0, bw, acc0, 0, 0, 0);
      acc1 = __builtin_amdgcn_mfma_f32_16x16x32_f16(*a1, bw, acc1, 0, 0, 0);
    }
    __syncthreads();
  }

  // phase A epilogue: clamp; write offbuf (LDS) + off_out (global, output #2)
  const int nA = nt * 16 + li;
  if (nA < 18) {
#pragma unroll
    for (int f = 0; f < 2; ++f) {
      int mf = mh * 2 + f;
      f32x4 a = f ? acc1 : acc0;
      float4 v;
      v.x = fminf(1.f, fmaxf(-1.f, a[0]));
      v.y = fminf(1.f, fmaxf(-1.f, a[1]));
      v.z = fminf(1.f, fmaxf(-1.f, a[2]));
      v.w = fminf(1.f, fmaxf(-1.f, a[3]));
      offbuf[(mf * 16 + lo * 4 + 0) * 19 + nA] = v.x;
      offbuf[(mf * 16 + lo * 4 + 1) * 19 + nA] = v.y;
      offbuf[(mf * 16 + lo * 4 + 2) * 19 + nA] = v.z;
      offbuf[(mf * 16 + lo * 4 + 3) * 19 + nA] = v.w;
      *(float4*)(off_out + ((b * 18 + nA) * HH + ty0 + mf) * WW + tx0 +
                 lo * 4) = v;
    }
  }
  __syncthreads();                      // offbuf ready

  // ================= phase B: deformable conv =================
  const int h = ty0 + wv, w = tx0 + li;
  const int m_pix = wv * 16 + li;
  int bs[3];
  bool tre[3];
  __half2 w00h[3], w01h[3], w10h[3], w11h[3];
#pragma unroll
  for (int kk = 0; kk < 3; ++kk) {
    int t = kk * 4 + lo;
    tre[kk] = (t < 9);
    if (tre[kk]) {
      float dy = offbuf[m_pix * 19 + 2 * t];
      float dx = offbuf[m_pix * 19 + 2 * t + 1];
      float pyf = (float)(h - 1 + t / 3) + dy;
      float pxf = (float)(w - 1 + t % 3) + dx;
      float y0 = floorf(pyf), x0 = floorf(pxf);
      float wy = pyf - y0, wx = pxf - x0;
      bs[kk] = (((int)y0 - (ty0 - 2)) * 21 + ((int)x0 - (tx0 - 2))) * 4;
      w00h[kk] = __float2half2_rn((1.f - wy) * (1.f - wx));
      w01h[kk] = __float2half2_rn((1.f - wy) * wx);
      w10h[kk] = __float2half2_rn(wy * (1.f - wx));
      w11h[kk] = __float2half2_rn(wy * wx);
    } else {
      bs[kk] = 0;
      w00h[kk] = w01h[kk] = w10h[kk] = w11h[kk] = __float2half2_rn(0.f);
    }
  }

  f32x4 acc[4];
#pragma unroll
  for (int i = 0; i < 4; ++i) acc[i] = f32x4{0.f, 0.f, 0.f, 0.f};

  union u4h { uint4 q; __half2 hh[4]; unsigned u[4]; f16x8 v; };

  for (int chunk = 0; chunk < 8; ++chunk) {
    f16x8 bw0 = Bp[((wv * 24 + chunk * 3 + 0) << 6) + lane];
    f16x8 bw1 = Bp[((wv * 24 + chunk * 3 + 1) << 6) + lane];
    f16x8 bw2 = Bp[((wv * 24 + chunk * 3 + 2) << 6) + lane];
#pragma unroll
    for (int i = 0; i < 3; ++i) {
      int l = tid + i * 256;
      if (l < 756) patch2[l] = gx[i];
    }
    __syncthreads();
    if (chunk < 7) {
      int nco = (chunk + 1) * CHSTRIDE;
#pragma unroll
      for (int i = 0; i < 3; ++i)
        gx[i] = gxk[i] ? packh2(x[gxo[i] + nco], x[gxo[i] + nco + HWD]) : 0u;
    }
#pragma unroll
    for (int kk = 0; kk < 3; ++kk) {
      u4h a;
      if (tre[kk]) {
        u4h q00, q01, q10, q11;
        q00.q = *(const uint4*)(patch2 + bs[kk]);        // corner (0,0) ch0-7
        q01.q = *(const uint4*)(patch2 + bs[kk] + 4);    // (0,1)
        q10.q = *(const uint4*)(patch2 + bs[kk] + 84);   // (1,0): +21px
        q11.q = *(const uint4*)(patch2 + bs[kk] + 88);   // (1,1)
#pragma unroll
        for (int j = 0; j < 4; ++j) {
          __half2 v = __hmul2(w00h[kk], q00.hh[j]);
          v = __hfma2(w01h[kk], q01.hh[j], v);
          v = __hfma2(w10h[kk], q10.hh[j], v);
          v = __hfma2(w11h[kk], q11.hh[j], v);
          a.hh[j] = v;
        }
      } else {
        a.u[0] = a.u[1] = a.u[2] = a.u[3] = 0u;
      }
      Af[((wv * 3 + kk) << 6) + lane] = a.v;
    }
    __syncthreads();
#pragma unroll
    for (int kk = 0; kk < 3; ++kk) {
      f16x8 bw = (kk == 0) ? bw0 : (kk == 1) ? bw1 : bw2;
#pragma unroll
      for (int mf = 0; mf < 4; ++mf)
        acc[mf] = __builtin_amdgcn_mfma_f32_16x16x32_f16(
            Af[((mf * 3 + kk) << 6) + lane], bw, acc[mf], 0, 0, 0);
    }
  }

  // epilogue: aligned float4 stores (pre-BN) + fused BN partial sums
  const int n = wv * 16 + li;
  float s = 0.f, s2 = 0.f;
#pragma unroll
  for (int mf = 0; mf < 4; ++mf) {
    float* po = out + ((b * 64 + n) * HH + ty0 + mf) * WW + tx0 + lo * 4;
    *(float4*)po = make_float4(acc[mf][0], acc[mf][1], acc[mf][2], acc[mf][3]);
#pragma unroll
    for (int r = 0; r < 4; ++r) {
      float v = acc[mf][r];
      s += v;
      s2 = fmaf(v, v, s2);
    }
  }
  s += __shfl_xor(s, 16);
  s += __shfl_xor(s, 32);
  s2 += __shfl_xor(s2, 16);
  s2 += __shfl_xor(s2, 32);
  if (lo == 0) {
    int slot = blockIdx.x & (NSLOT - 1);
    atomicAdd(&part[n * NSLOT + slot], s);
    atomicAdd(&part[(64 + n) * NSLOT + slot], s2);
  }
}

// ---------------------------------------------------------------------------
// bn_final: fused reduce + BN apply + ReLU. Each block serves ONE channel
// (block spans 256 float4 within a 6400-float4 slice; 6400%256==0), redundantly
// reduces that channel's 256 partial slots (2KB, L2-hit), then applies BN.
// ---------------------------------------------------------------------------
__global__ __launch_bounds__(256) void bn_final_kernel(
    float* __restrict__ out, const float* __restrict__ part,
    const float* __restrict__ gamma, const float* __restrict__ beta) {
  const int i = blockIdx.x * 256 + threadIdx.x;  // float4 index
  const int o = (i / (HWD / 4)) & 63;            // uniform per block
  const int tid = threadIdx.x, wv = tid >> 6;

  float s = part[o * NSLOT + tid];
  float s2 = part[(64 + o) * NSLOT + tid];
#pragma unroll
  for (int sh = 1; sh < 64; sh <<= 1) {
    s += __shfl_xor(s, sh);
    s2 += __shfl_xor(s2, sh);
  }
  __shared__ float red[8];
  if ((tid & 63) == 0) { red[wv] = s; red[4 + wv] = s2; }
  __syncthreads();
  s = red[0] + red[1] + red[2] + red[3];
  s2 = red[4] + red[5] + red[6] + red[7];

  const float n_inv = 1.0f / (float)(BB * HWD);
  float mean = s * n_inv;
  float var = s2 * n_inv - mean * mean;
  float inv = gamma[o] * rsqrtf(var + EPSBN);
  float bt = beta[o];
  float4 v = ((float4*)out)[i];
  v.x = fmaxf(0.f, (v.x - mean) * inv + bt);
  v.y = fmaxf(0.f, (v.y - mean) * inv + bt);
  v.z = fmaxf(0.f, (v.z - mean) * inv + bt);
  v.w = fmaxf(0.f, (v.w - mean) * inv + bt);
  ((float4*)out)[i] = v;
}

extern "C" void kernel_launch(void* const* d_in, const int* in_sizes, int n_in,
                              void* d_out, int out_size, void* d_ws, size_t ws_size,
                              hipStream_t stream) {
  const float* x = (const float*)d_in[0];
  const float* d = (const float*)d_in[1];
  const float* ow = (const float*)d_in[2];
  const float* cw = (const float*)d_in[3];
  const float* gamma = (const float*)d_in[4];
  const float* beta = (const float*)d_in[5];

  float* out = (float*)d_out;
  float* off_out = out + OUT_ELEMS;

  // ws: Bp ush[49152] | B2p ush[24576] | part f32[32768]
  unsigned short* Bp = (unsigned short*)d_ws;
  unsigned short* B2p = Bp + 49152;
  float* part = (float*)(B2p + 24576);

  prep_kernel<<<192, 256, 0, stream>>>(cw, ow, Bp, B2p, part);

  fused_kernel<<<1600, 256, 0, stream>>>(
      x, d, (const f16x8*)Bp, (const f16x8*)B2p, out, off_out, part);

  bn_final_kernel<<<OUT_ELEMS / 4 / 256, 256, 0, stream>>>(
      out, part, gamma, beta);
}